// Round 3
// baseline (253.473 us; speedup 1.0000x reference)
//
#include <hip/hip_runtime.h>
#include <math.h>

// GMM sufficient statistics + energy, MI355X (gfx950), bf16 MFMA path.
//
// Pipeline: prep (convert/transpose) -> stats (SYRK via mfma_f32_16x16x32_bf16)
//           -> reduce (sum partials, assemble sigma)
//           -> cholinv (Cholesky, U=L^-1, constants)  [batched LDS access]
//           -> energy (V = Z U^T via MFMA, online logsumexp).

#define NR 65536
#define NCOMP 16
#define DDIM 64
#define JITTER 1e-6f
#define LOG2PI 1.83787706640934548356f  // ln(2*pi)

typedef float f32x4 __attribute__((ext_vector_type(4)));
typedef short s16x8 __attribute__((ext_vector_type(8)));
typedef unsigned short u16x4 __attribute__((ext_vector_type(4)));

// ws layout (bytes)
#define OFF_ZBF 0ul            // z bf16 row-major [N][64]            : 8 MiB
#define OFF_ZT  (8ul << 20)    // z bf16 transposed [64][N]           : 8 MiB
#define OFF_SG  (16ul << 20)   // sqrt(gamma) bf16 transposed [16][N] : 2 MiB
#define OFF_S2P (18ul << 20)   // S2 partials f32 [32][16][4096]      : 8 MiB
#define OFF_SIG (26ul << 20)   // sigma f32 [16][4096]                : 256 KiB
#define OFF_UBF (27ul << 20)   // U bf16 [16][64][64]                 : 128 KiB
#define OFF_F32 (28ul << 20)   // gsum[16], s1[1024], tvec[1024], constk[16]

__device__ __forceinline__ float b2f(unsigned short u) {
  return __uint_as_float(((unsigned)u) << 16);
}
__device__ __forceinline__ unsigned short f2bs(float f) {
  unsigned u = __float_as_uint(f);
  return (unsigned short)((u + 0x7fffu + ((u >> 16) & 1u)) >> 16);
}

// ---------------------------------------------------------------- prep -----
// 256 blocks x 256 threads; block handles 256 rows.
__global__ __launch_bounds__(256) void prep_kernel(
    const float* __restrict__ z, const float* __restrict__ gamma,
    unsigned short* __restrict__ zbf, unsigned short* __restrict__ ztbf,
    unsigned short* __restrict__ sgbf, float* __restrict__ gsum,
    float* __restrict__ s1) {
  __shared__ unsigned short zt[256][64];  // bf16 copy of tile
  __shared__ float gt[256][16];
  __shared__ float red[16][16];
  const int t = threadIdx.x;
  const long base = (long)blockIdx.x * 256;

  const float4* z4 = (const float4*)(z + base * 64);
  for (int i = t; i < 4096; i += 256) {
    float4 v = z4[i];
    u16x4 o;
    o[0] = f2bs(v.x); o[1] = f2bs(v.y); o[2] = f2bs(v.z); o[3] = f2bs(v.w);
    int r = i >> 4, c = (i & 15) * 4;
    zt[r][c] = o[0]; zt[r][c + 1] = o[1]; zt[r][c + 2] = o[2]; zt[r][c + 3] = o[3];
    *(u16x4*)(zbf + base * 64 + (long)i * 4) = o;
  }
  const float4* g4 = (const float4*)(gamma + base * 16);
  for (int i = t; i < 1024; i += 256) {
    float4 v = g4[i];
    int r = i >> 2, c = (i & 3) * 4;
    gt[r][c] = v.x; gt[r][c + 1] = v.y; gt[r][c + 2] = v.z; gt[r][c + 3] = v.w;
  }
  __syncthreads();

  // transposed z (bf16): ZT[l][r]
  {
    int l = t >> 2, rp = t & 3;
    for (int j8 = 0; j8 < 64; j8 += 8) {
      s16x8 o;
#pragma unroll
      for (int u2 = 0; u2 < 8; ++u2) o[u2] = (short)zt[rp * 64 + j8 + u2][l];
      *(s16x8*)(ztbf + (long)l * NR + base + rp * 64 + j8) = o;
    }
  }
  // transposed sqrt(gamma) (bf16): SG[k][r]
  if (t < 128) {
    int k = t >> 3, rp = t & 7;
    for (int j8 = 0; j8 < 32; j8 += 8) {
      s16x8 o;
#pragma unroll
      for (int u2 = 0; u2 < 8; ++u2)
        o[u2] = (short)f2bs(sqrtf(gt[rp * 32 + j8 + u2][k]));
      *(s16x8*)(sgbf + (long)k * NR + base + rp * 32 + j8) = o;
    }
  }
  // gamma_sum partial (fp32 exact)
  {
    int k = t & 15, rp = t >> 4;
    float s = 0.f;
#pragma unroll
    for (int j = 0; j < 16; ++j) s += gt[rp * 16 + j][k];
    red[k][rp] = s;
  }
  __syncthreads();
  if (t < 16) {
    float s = 0.f;
#pragma unroll
    for (int c = 0; c < 16; ++c) s += red[t][c];
    atomicAdd(&gsum[t], s);
  }
  // S1[k][l] = sum_r gamma[r][k] * z[r][l]  (fp32 accumulate)
  {
    int l = t & 63, kq = t >> 6;
    float a0 = 0.f, a1 = 0.f, a2 = 0.f, a3 = 0.f;
    for (int r = 0; r < 256; ++r) {
      float zv = b2f(zt[r][l]);
      const float4 gv = *(const float4*)&gt[r][kq * 4];
      a0 = fmaf(gv.x, zv, a0); a1 = fmaf(gv.y, zv, a1);
      a2 = fmaf(gv.z, zv, a2); a3 = fmaf(gv.w, zv, a3);
    }
    atomicAdd(&s1[(kq * 4 + 0) * 64 + l], a0);
    atomicAdd(&s1[(kq * 4 + 1) * 64 + l], a1);
    atomicAdd(&s1[(kq * 4 + 2) * 64 + l], a2);
    atomicAdd(&s1[(kq * 4 + 3) * 64 + l], a3);
  }
}

// --------------------------------------------------------------- stats -----
// 512 blocks (32 row-chunks x 16 components, XCD-swizzled) x 256 threads.
__global__ __launch_bounds__(256) void stats_kernel(
    const unsigned short* __restrict__ ztbf,
    const unsigned short* __restrict__ sgbf, float* __restrict__ s2p) {
  __shared__ float s2w[4][4096];
  const int t = threadIdx.x;
  const int bid = blockIdx.x;
  const int xcd = bid & 7, gi = bid >> 3;
  const int chunk = xcd * 4 + (gi & 3);  // 0..31
  const int comp = gi >> 2;              // 0..15
  const int w = t >> 6, la = t & 15, hi = (t & 63) >> 4;
  const long rbase = (long)chunk * 2048 + w * 512;
  f32x4 acc[4][4];
#pragma unroll
  for (int a = 0; a < 4; ++a)
#pragma unroll
    for (int b2 = 0; b2 < 4; ++b2) acc[a][b2] = (f32x4){0.f, 0.f, 0.f, 0.f};

  for (int ks = 0; ks < 16; ++ks) {
    const long r0 = rbase + ks * 32 + hi * 8;
    s16x8 sa = *(const s16x8*)(sgbf + (long)comp * NR + r0);
    float saf[8];
#pragma unroll
    for (int u2 = 0; u2 < 8; ++u2) saf[u2] = b2f((unsigned short)sa[u2]);
    s16x8 sq[4];
#pragma unroll
    for (int T = 0; T < 4; ++T) {
      s16x8 zv = *(const s16x8*)(ztbf + (long)(T * 16 + la) * NR + r0);
#pragma unroll
      for (int u2 = 0; u2 < 8; ++u2)
        sq[T][u2] = (short)f2bs(b2f((unsigned short)zv[u2]) * saf[u2]);
    }
#pragma unroll
    for (int a = 0; a < 4; ++a)
#pragma unroll
      for (int b2 = 0; b2 < 4; ++b2)
        acc[a][b2] = __builtin_amdgcn_mfma_f32_16x16x32_bf16(sq[a], sq[b2],
                                                             acc[a][b2], 0, 0, 0);
  }
  // C/D layout: col = lane&15, row = (lane>>4)*4 + reg (HW-verified)
#pragma unroll
  for (int a = 0; a < 4; ++a)
#pragma unroll
    for (int b2 = 0; b2 < 4; ++b2)
#pragma unroll
      for (int rg = 0; rg < 4; ++rg)
        s2w[w][(a * 16 + hi * 4 + rg) * 64 + b2 * 16 + la] = acc[a][b2][rg];
  __syncthreads();
  float* outp = s2p + ((long)chunk * NCOMP + comp) * 4096;
  for (int i = t; i < 4096; i += 256)
    outp[i] = (s2w[0][i] + s2w[1][i]) + (s2w[2][i] + s2w[3][i]);
}

// --------------------------------------------------------------- reduce ----
// 256 blocks x 256 threads: sum the 32 chunk partials, assemble sigma.
__global__ __launch_bounds__(256) void reduce_kernel(
    const float* __restrict__ s2p, const float* __restrict__ gsum,
    const float* __restrict__ s1, float* __restrict__ sigf) {
  const int tid = blockIdx.x * 256 + threadIdx.x;  // 0..65535
  const int k = tid >> 12, i = tid & 4095;
  float s = 0.f;
#pragma unroll 8
  for (int c = 0; c < 32; ++c) s += s2p[((long)c * NCOMP + k) * 4096 + i];
  const float gs = gsum[k];
  const int a = i >> 6, b = i & 63;
  const float mua = s1[k * 64 + a] / gs;
  const float mub = s1[k * 64 + b] / gs;
  float v = s / gs - mua * mub;
  if (a == b) v += JITTER;
  sigf[k * 4096 + i] = v;
}

// -------------------------------------------------------------- cholinv ----
// 16 blocks x 256 threads. All LDS traffic is explicitly batched:
// per step, 16 broadcast reads + 16 lane-consecutive reads issue together
// under one waitcnt (no read-modify-write chains), then FMAs, then writes.
// OOB lanes read wrapped (&63) addresses that land in never-written-this-step
// regions (upper triangle / already-final columns) — safe, discarded.
__global__ __launch_bounds__(256) void cholinv_kernel(
    const float* __restrict__ sigf, const float* __restrict__ gsum,
    const float* __restrict__ s1, unsigned short* __restrict__ ubf,
    float* __restrict__ tvec, float* __restrict__ constk) {
  __shared__ float sig[64][65];   // A (full), then lazy-Cholesky, then L
  __shared__ float uu[64][65];    // U = L^{-1}
  __shared__ float ps[64][65];    // inversion partial sums / scratch
  __shared__ float dinv[64], lg_s[64], mu_s[64];
  const int t = threadIdx.x, k = blockIdx.x;
  const int i2 = t & 63, q = t >> 6;
  const float gs = gsum[k];
  for (int i = t; i < 4096; i += 256) sig[i >> 6][i & 63] = sigf[k * 4096 + i];
  if (t < 64) mu_s[t] = s1[k * 64 + t] / gs;
  __syncthreads();

  // ---- Cholesky, lazy-scaled (pivot division folded into the update) ----
  // Invariant: lower triangle holds A'[i][j] = L[i][j]*L[j][j]; diag = L_jj^2.
  for (int j = 0; j < 63; ++j) {
    const float inv = 1.0f / sig[j][j];      // broadcast read
    const float li = sig[i2][j] * inv;       // lane-consecutive read
    float cj[16], av[16];
#pragma unroll
    for (int u = 0; u < 16; ++u) {
      const int mc = (j + 1 + q + 4 * u) & 63;
      cj[u] = sig[mc][j];                    // wave-uniform -> LDS broadcast
      av[u] = sig[i2][mc];                   // stride-65 -> conflict-free
    }
#pragma unroll
    for (int u = 0; u < 16; ++u) {
      const int m = j + 1 + q + 4 * u;
      if (m <= i2) sig[i2][m] = av[u] - li * cj[u];
    }
    __syncthreads();
  }
  // diagonal, logdet terms
  if (t < 64) {
    const float sv = sig[t][t];
    dinv[t] = 1.0f / sqrtf(sv);
    lg_s[t] = 0.5f * logf(sv);
  }
  __syncthreads();
  // column scaling: sig[i][j] *= dinv[j]  (thread (q,i2) scales column i2)
  {
    const float dj = dinv[i2];
    float tv[16];
#pragma unroll
    for (int u = 0; u < 16; ++u) tv[u] = sig[q + 4 * u][i2];
#pragma unroll
    for (int u = 0; u < 16; ++u) {
      const int i = q + 4 * u;
      if (i2 < i) sig[i][i2] = tv[u] * dj;   // now sig holds L below diag
    }
  }
  // zero inversion accumulators
  for (int idx = t; idx < 64 * 65; idx += 256) ((float*)ps)[idx] = 0.f;
  __syncthreads();

  // ---- U = L^{-1}, outer-product forward substitution, batched ----
  for (int i = 0; i < 64; ++i) {
    const float val = (((i2 == i) ? 1.f : 0.f) - ps[i][i2]) * dinv[i];
    if (q == 0) uu[i][i2] = val;
    float sv[16], pv[16];
#pragma unroll
    for (int u = 0; u < 16; ++u) {
      const int ipc = (i + 1 + q + 4 * u) & 63;
      sv[u] = sig[ipc][i];                   // wave-uniform -> broadcast
      pv[u] = ps[ipc][i2];                   // lane-consecutive
    }
#pragma unroll
    for (int u = 0; u < 16; ++u) {
      const int ip = i + 1 + q + 4 * u;
      if (ip < 64) ps[ip][i2] = pv[u] + sv[u] * val;
    }
    __syncthreads();
  }

  // ---- outputs ----
  for (int idx = t; idx < 4096; idx += 256)
    ubf[k * 4096 + idx] = f2bs(uu[idx >> 6][idx & 63]);
  // t_k = U_bf16 * mu (use rounded U for consistency with energy's operand)
  {
    float s = 0.f;
#pragma unroll 4
    for (int l = q; l < 64; l += 4) s = fmaf(b2f(f2bs(uu[i2][l])), mu_s[l], s);
    __syncthreads();  // ps free for reuse as [4][64] scratch
    ps[q][i2] = s;
  }
  __syncthreads();
  if (t < 64)
    tvec[k * 64 + t] = ps[0][t] + ps[1][t] + ps[2][t] + ps[3][t];
  if (t == 0) {
    float ld = 0.f;
#pragma unroll 8
    for (int j = 0; j < 64; ++j) ld += lg_s[j];
    constk[k] = logf(gs / (float)NR) + 64.f * LOG2PI + 2.f * ld;
  }
}

// --------------------------------------------------------------- energy ----
// 512 blocks x 256 threads; block = 128 rows, wave = 32 rows. No LDS:
// A (z) and B (U) fragments load straight from global (L1/L2 resident).
__global__ __launch_bounds__(256) void energy_kernel(
    const unsigned short* __restrict__ zbf, const unsigned short* __restrict__ ubf,
    const float* __restrict__ tvec, const float* __restrict__ constk,
    float* __restrict__ out) {
  const int t = threadIdx.x;
  const int w = t >> 6, la = t & 15, hi = (t & 63) >> 4;
  const long r0 = (long)blockIdx.x * 128 + w * 32;
  float M[2][4], S[2][4];
#pragma unroll
  for (int rs = 0; rs < 2; ++rs)
#pragma unroll
    for (int rg = 0; rg < 4; ++rg) { M[rs][rg] = -3.0e38f; S[rs][rg] = 0.f; }

  for (int comp = 0; comp < NCOMP; ++comp) {
    float tvv[4];
#pragma unroll
    for (int mt = 0; mt < 4; ++mt) tvv[mt] = tvec[comp * 64 + mt * 16 + la];
    const float cst = constk[comp];
    f32x4 acc[2][4];
#pragma unroll
    for (int rs = 0; rs < 2; ++rs)
#pragma unroll
      for (int mt = 0; mt < 4; ++mt) acc[rs][mt] = (f32x4){0.f, 0.f, 0.f, 0.f};
#pragma unroll
    for (int ks = 0; ks < 2; ++ks) {
      const int l0 = ks * 32 + hi * 8;
      s16x8 za[2], ub[4];
#pragma unroll
      for (int rs = 0; rs < 2; ++rs)
        za[rs] = *(const s16x8*)(zbf + (r0 + rs * 16 + la) * 64 + l0);
#pragma unroll
      for (int mt = 0; mt < 4; ++mt)
        ub[mt] = *(const s16x8*)(ubf + ((long)comp * 64 + mt * 16 + la) * 64 + l0);
#pragma unroll
      for (int rs = 0; rs < 2; ++rs)
#pragma unroll
        for (int mt = 0; mt < 4; ++mt)
          acc[rs][mt] = __builtin_amdgcn_mfma_f32_16x16x32_bf16(za[rs], ub[mt],
                                                                acc[rs][mt], 0, 0, 0);
    }
    // q = sum_m (V[r][m] - t_m)^2 ; reduce across the 16-lane column group
#pragma unroll
    for (int rs = 0; rs < 2; ++rs)
#pragma unroll
      for (int rg = 0; rg < 4; ++rg) {
        float qv = 0.f;
#pragma unroll
        for (int mt = 0; mt < 4; ++mt) {
          float d0 = acc[rs][mt][rg] - tvv[mt];
          qv = fmaf(d0, d0, qv);
        }
        qv += __shfl_xor(qv, 1);
        qv += __shfl_xor(qv, 2);
        qv += __shfl_xor(qv, 4);
        qv += __shfl_xor(qv, 8);
        float lg = cst - 0.5f * qv;
        float Mn = fmaxf(M[rs][rg], lg);
        S[rs][rg] = S[rs][rg] * __expf(M[rs][rg] - Mn) + __expf(lg - Mn);
        M[rs][rg] = Mn;
      }
  }
  if (la == 0) {
#pragma unroll
    for (int rs = 0; rs < 2; ++rs)
#pragma unroll
      for (int rg = 0; rg < 4; ++rg)
        out[r0 + rs * 16 + hi * 4 + rg] = -(M[rs][rg] + __logf(S[rs][rg]));
  }
}

// ---------------------------------------------------------------------------
extern "C" void kernel_launch(void* const* d_in, const int* in_sizes, int n_in,
                              void* d_out, int out_size, void* d_ws, size_t ws_size,
                              hipStream_t stream) {
  const float* z = (const float*)d_in[0];
  const float* gamma = (const float*)d_in[1];
  float* out = (float*)d_out;
  char* ws = (char*)d_ws;
  unsigned short* zbf = (unsigned short*)(ws + OFF_ZBF);
  unsigned short* ztbf = (unsigned short*)(ws + OFF_ZT);
  unsigned short* sgbf = (unsigned short*)(ws + OFF_SG);
  float* s2p = (float*)(ws + OFF_S2P);
  float* sigf = (float*)(ws + OFF_SIG);
  unsigned short* ubf = (unsigned short*)(ws + OFF_UBF);
  float* f32a = (float*)(ws + OFF_F32);
  float* gsum = f32a;
  float* s1 = f32a + 16;
  float* tvec = f32a + 16 + 1024;
  float* ck = f32a + 16 + 2048;

  hipMemsetAsync(gsum, 0, (16 + 1024) * sizeof(float), stream);
  hipLaunchKernelGGL(prep_kernel, dim3(256), dim3(256), 0, stream,
                     z, gamma, zbf, ztbf, sgbf, gsum, s1);
  hipLaunchKernelGGL(stats_kernel, dim3(512), dim3(256), 0, stream,
                     ztbf, sgbf, s2p);
  hipLaunchKernelGGL(reduce_kernel, dim3(256), dim3(256), 0, stream,
                     s2p, gsum, s1, sigf);
  hipLaunchKernelGGL(cholinv_kernel, dim3(16), dim3(256), 0, stream,
                     sigf, gsum, s1, ubf, tvec, ck);
  hipLaunchKernelGGL(energy_kernel, dim3(512), dim3(256), 0, stream,
                     zbf, ubf, tvec, ck, out);
}

// Round 5
// 161.196 us; speedup vs baseline: 1.5725x; 1.5725x over previous
//
#include <hip/hip_runtime.h>
#include <math.h>

// GMM sufficient statistics + energy, MI355X (gfx950), bf16 MFMA path.
//
// Pipeline: prep (convert/transpose) -> stats (SYRK via mfma_f32_16x16x32_bf16)
//           -> reduce (sum partials, assemble sigma)
//           -> cholinv (fused register-only Cholesky + L^-1, 1 wave/component)
//           -> energy (V = Z U^T via MFMA, online logsumexp).

#define NR 65536
#define NCOMP 16
#define DDIM 64
#define JITTER 1e-6f
#define LOG2PI 1.83787706640934548356f  // ln(2*pi)

typedef float f32x4 __attribute__((ext_vector_type(4)));
typedef short s16x8 __attribute__((ext_vector_type(8)));
typedef unsigned short u16x4 __attribute__((ext_vector_type(4)));

// ws layout (bytes)
#define OFF_ZBF 0ul            // z bf16 row-major [N][64]            : 8 MiB
#define OFF_ZT  (8ul << 20)    // z bf16 transposed [64][N]           : 8 MiB
#define OFF_SG  (16ul << 20)   // sqrt(gamma) bf16 transposed [16][N] : 2 MiB
#define OFF_S2P (18ul << 20)   // S2 partials f32 [32][16][4096]      : 8 MiB
#define OFF_SIG (26ul << 20)   // sigma f32 [16][4096]                : 256 KiB
#define OFF_UBF (27ul << 20)   // U bf16 [16][64][64]                 : 128 KiB
#define OFF_F32 (28ul << 20)   // gsum[16], s1[1024], tvec[1024], constk[16]

__device__ __forceinline__ float b2f(unsigned short u) {
  return __uint_as_float(((unsigned)u) << 16);
}
__device__ __forceinline__ unsigned short f2bs(float f) {
  unsigned u = __float_as_uint(f);
  return (unsigned short)((u + 0x7fffu + ((u >> 16) & 1u)) >> 16);
}

// ---------------------------------------------------------------- prep -----
// 256 blocks x 256 threads; block handles 256 rows.
__global__ __launch_bounds__(256) void prep_kernel(
    const float* __restrict__ z, const float* __restrict__ gamma,
    unsigned short* __restrict__ zbf, unsigned short* __restrict__ ztbf,
    unsigned short* __restrict__ sgbf, float* __restrict__ gsum,
    float* __restrict__ s1) {
  __shared__ unsigned short zt[256][64];  // bf16 copy of tile
  __shared__ float gt[256][16];
  __shared__ float red[16][16];
  const int t = threadIdx.x;
  const long base = (long)blockIdx.x * 256;

  const float4* z4 = (const float4*)(z + base * 64);
  for (int i = t; i < 4096; i += 256) {
    float4 v = z4[i];
    u16x4 o;
    o[0] = f2bs(v.x); o[1] = f2bs(v.y); o[2] = f2bs(v.z); o[3] = f2bs(v.w);
    int r = i >> 4, c = (i & 15) * 4;
    zt[r][c] = o[0]; zt[r][c + 1] = o[1]; zt[r][c + 2] = o[2]; zt[r][c + 3] = o[3];
    *(u16x4*)(zbf + base * 64 + (long)i * 4) = o;
  }
  const float4* g4 = (const float4*)(gamma + base * 16);
  for (int i = t; i < 1024; i += 256) {
    float4 v = g4[i];
    int r = i >> 2, c = (i & 3) * 4;
    gt[r][c] = v.x; gt[r][c + 1] = v.y; gt[r][c + 2] = v.z; gt[r][c + 3] = v.w;
  }
  __syncthreads();

  // transposed z (bf16): ZT[l][r]
  {
    int l = t >> 2, rp = t & 3;
    for (int j8 = 0; j8 < 64; j8 += 8) {
      s16x8 o;
#pragma unroll
      for (int u2 = 0; u2 < 8; ++u2) o[u2] = (short)zt[rp * 64 + j8 + u2][l];
      *(s16x8*)(ztbf + (long)l * NR + base + rp * 64 + j8) = o;
    }
  }
  // transposed sqrt(gamma) (bf16): SG[k][r]
  if (t < 128) {
    int k = t >> 3, rp = t & 7;
    for (int j8 = 0; j8 < 32; j8 += 8) {
      s16x8 o;
#pragma unroll
      for (int u2 = 0; u2 < 8; ++u2)
        o[u2] = (short)f2bs(sqrtf(gt[rp * 32 + j8 + u2][k]));
      *(s16x8*)(sgbf + (long)k * NR + base + rp * 32 + j8) = o;
    }
  }
  // gamma_sum partial (fp32 exact)
  {
    int k = t & 15, rp = t >> 4;
    float s = 0.f;
#pragma unroll
    for (int j = 0; j < 16; ++j) s += gt[rp * 16 + j][k];
    red[k][rp] = s;
  }
  __syncthreads();
  if (t < 16) {
    float s = 0.f;
#pragma unroll
    for (int c = 0; c < 16; ++c) s += red[t][c];
    atomicAdd(&gsum[t], s);
  }
  // S1[k][l] = sum_r gamma[r][k] * z[r][l]  (fp32 accumulate)
  {
    int l = t & 63, kq = t >> 6;
    float a0 = 0.f, a1 = 0.f, a2 = 0.f, a3 = 0.f;
    for (int r = 0; r < 256; ++r) {
      float zv = b2f(zt[r][l]);
      const float4 gv = *(const float4*)&gt[r][kq * 4];
      a0 = fmaf(gv.x, zv, a0); a1 = fmaf(gv.y, zv, a1);
      a2 = fmaf(gv.z, zv, a2); a3 = fmaf(gv.w, zv, a3);
    }
    atomicAdd(&s1[(kq * 4 + 0) * 64 + l], a0);
    atomicAdd(&s1[(kq * 4 + 1) * 64 + l], a1);
    atomicAdd(&s1[(kq * 4 + 2) * 64 + l], a2);
    atomicAdd(&s1[(kq * 4 + 3) * 64 + l], a3);
  }
}

// --------------------------------------------------------------- stats -----
// 512 blocks (32 row-chunks x 16 components, XCD-swizzled) x 256 threads.
__global__ __launch_bounds__(256) void stats_kernel(
    const unsigned short* __restrict__ ztbf,
    const unsigned short* __restrict__ sgbf, float* __restrict__ s2p) {
  __shared__ float s2w[4][4096];
  const int t = threadIdx.x;
  const int bid = blockIdx.x;
  const int xcd = bid & 7, gi = bid >> 3;
  const int chunk = xcd * 4 + (gi & 3);  // 0..31
  const int comp = gi >> 2;              // 0..15
  const int w = t >> 6, la = t & 15, hi = (t & 63) >> 4;
  const long rbase = (long)chunk * 2048 + w * 512;
  f32x4 acc[4][4];
#pragma unroll
  for (int a = 0; a < 4; ++a)
#pragma unroll
    for (int b2 = 0; b2 < 4; ++b2) acc[a][b2] = (f32x4){0.f, 0.f, 0.f, 0.f};

  for (int ks = 0; ks < 16; ++ks) {
    const long r0 = rbase + ks * 32 + hi * 8;
    s16x8 sa = *(const s16x8*)(sgbf + (long)comp * NR + r0);
    float saf[8];
#pragma unroll
    for (int u2 = 0; u2 < 8; ++u2) saf[u2] = b2f((unsigned short)sa[u2]);
    s16x8 sq[4];
#pragma unroll
    for (int T = 0; T < 4; ++T) {
      s16x8 zv = *(const s16x8*)(ztbf + (long)(T * 16 + la) * NR + r0);
#pragma unroll
      for (int u2 = 0; u2 < 8; ++u2)
        sq[T][u2] = (short)f2bs(b2f((unsigned short)zv[u2]) * saf[u2]);
    }
#pragma unroll
    for (int a = 0; a < 4; ++a)
#pragma unroll
      for (int b2 = 0; b2 < 4; ++b2)
        acc[a][b2] = __builtin_amdgcn_mfma_f32_16x16x32_bf16(sq[a], sq[b2],
                                                             acc[a][b2], 0, 0, 0);
  }
  // C/D layout: col = lane&15, row = (lane>>4)*4 + reg (HW-verified)
#pragma unroll
  for (int a = 0; a < 4; ++a)
#pragma unroll
    for (int b2 = 0; b2 < 4; ++b2)
#pragma unroll
      for (int rg = 0; rg < 4; ++rg)
        s2w[w][(a * 16 + hi * 4 + rg) * 64 + b2 * 16 + la] = acc[a][b2][rg];
  __syncthreads();
  float* outp = s2p + ((long)chunk * NCOMP + comp) * 4096;
  for (int i = t; i < 4096; i += 256)
    outp[i] = (s2w[0][i] + s2w[1][i]) + (s2w[2][i] + s2w[3][i]);
}

// --------------------------------------------------------------- reduce ----
// 256 blocks x 256 threads: sum the 32 chunk partials, assemble sigma.
__global__ __launch_bounds__(256) void reduce_kernel(
    const float* __restrict__ s2p, const float* __restrict__ gsum,
    const float* __restrict__ s1, float* __restrict__ sigf) {
  const int tid = blockIdx.x * 256 + threadIdx.x;  // 0..65535
  const int k = tid >> 12, i = tid & 4095;
  float s = 0.f;
#pragma unroll 8
  for (int c = 0; c < 32; ++c) s += s2p[((long)c * NCOMP + k) * 4096 + i];
  const float gs = gsum[k];
  const int a = i >> 6, b = i & 63;
  const float mua = s1[k * 64 + a] / gs;
  const float mub = s1[k * 64 + b] / gs;
  float v = s / gs - mua * mub;
  if (a == b) v += JITTER;
  sigf[k * 4096 + i] = v;
}

// -------------------------------------------------------------- cholinv ----
// 16 blocks x 64 threads (1 wave per component). Fused left-looking
// Cholesky + forward-substitution (U = L^-1), fully unrolled so every
// array index is compile-time: col/lr/ux live entirely in VGPRs. Cross-lane
// row broadcasts are v_readlane with STATIC lane index — no LDS, no
// barriers, no address arithmetic in the serial chain.
//
// Lane c owns column c: col[m]=Sigma[m][c]; lr[j]=L[c][j]; ux[j]=U[j][c].
// Upper-triangle lanes (c<j) accumulate garbage in lr/cj, but readlane only
// ever targets lane j's valid jp<j region, and ux stays exact-zero above
// the diagonal by induction, so garbage never reaches any output.
__global__ __launch_bounds__(64) void cholinv_kernel(
    const float* __restrict__ sigf, const float* __restrict__ gsum,
    const float* __restrict__ s1, unsigned short* __restrict__ ubf,
    float* __restrict__ tvec, float* __restrict__ constk) {
  __shared__ float Ut[64][66];   // rounded U rows, for tvec row-dots
  __shared__ float mu_s[64];
  const int c = threadIdx.x;     // 0..63 == column index
  const int k = blockIdx.x;
  const float gs = gsum[k];
  mu_s[c] = s1[k * 64 + c] / gs;

  float col[64], lr[64], ux[64];
  const float* sk = sigf + k * 4096;
#pragma unroll
  for (int m = 0; m < 64; ++m) col[m] = sk[m * 64 + c];

  float ld = 0.f;  // uniform: sum log2(pivot)
#pragma unroll
  for (int j = 0; j < 64; ++j) {
    float cj = col[j];           // A[j][c] (symmetric: = A[c][j])
    float ax = 0.f;
#pragma unroll
    for (int jp = 0; jp < j; ++jp) {
      const float b = __uint_as_float(
          __builtin_amdgcn_readlane(__float_as_uint(lr[jp]), j));  // L[j][jp]
      cj = fmaf(-b, lr[jp], cj);   // chol dot:  A[j][c] - sum L[j][.]L[c][.]
      ax = fmaf(-b, ux[jp], ax);   // fwd-sub:  -sum L[j][.] x[.]
    }
    const float p = __uint_as_float(
        __builtin_amdgcn_readlane(__float_as_uint(cj), j));  // pivot L_jj^2
    const float dinv = rsqrtf(p);
    ld += __log2f(p);
    lr[j] = cj * dinv;                                  // L[c][j] (diag ok)
    ux[j] = (((c == j) ? 1.f : 0.f) + ax) * dinv;       // U[j][c]
  }

  // ---- outputs ----
#pragma unroll
  for (int j = 0; j < 64; ++j) {
    const unsigned short ub = f2bs(ux[j]);
    Ut[j][c] = b2f(ub);                       // rounded copy (lane-consec)
    ubf[k * 4096 + j * 64 + c] = ub;          // row-major U, coalesced 2B
  }
  __syncthreads();
  // tvec[m] = sum_l Ubf16[m][l] * mu[l]  (lane m computes row m)
  float s = 0.f;
#pragma unroll
  for (int l = 0; l < 64; ++l) s = fmaf(Ut[c][l], mu_s[l], s);
  tvec[k * 64 + c] = s;
  if (c == 0)
    constk[k] = logf(gs / (float)NR) + 64.f * LOG2PI
                + 0.69314718055994530942f * ld;
}

// --------------------------------------------------------------- energy ----
// 512 blocks x 256 threads; block = 128 rows, wave = 32 rows. No LDS:
// A (z) and B (U) fragments load straight from global (L1/L2 resident).
__global__ __launch_bounds__(256) void energy_kernel(
    const unsigned short* __restrict__ zbf, const unsigned short* __restrict__ ubf,
    const float* __restrict__ tvec, const float* __restrict__ constk,
    float* __restrict__ out) {
  const int t = threadIdx.x;
  const int w = t >> 6, la = t & 15, hi = (t & 63) >> 4;
  const long r0 = (long)blockIdx.x * 128 + w * 32;
  float M[2][4], S[2][4];
#pragma unroll
  for (int rs = 0; rs < 2; ++rs)
#pragma unroll
    for (int rg = 0; rg < 4; ++rg) { M[rs][rg] = -3.0e38f; S[rs][rg] = 0.f; }

  for (int comp = 0; comp < NCOMP; ++comp) {
    float tvv[4];
#pragma unroll
    for (int mt = 0; mt < 4; ++mt) tvv[mt] = tvec[comp * 64 + mt * 16 + la];
    const float cst = constk[comp];
    f32x4 acc[2][4];
#pragma unroll
    for (int rs = 0; rs < 2; ++rs)
#pragma unroll
      for (int mt = 0; mt < 4; ++mt) acc[rs][mt] = (f32x4){0.f, 0.f, 0.f, 0.f};
#pragma unroll
    for (int ks = 0; ks < 2; ++ks) {
      const int l0 = ks * 32 + hi * 8;
      s16x8 za[2], ub[4];
#pragma unroll
      for (int rs = 0; rs < 2; ++rs)
        za[rs] = *(const s16x8*)(zbf + (r0 + rs * 16 + la) * 64 + l0);
#pragma unroll
      for (int mt = 0; mt < 4; ++mt)
        ub[mt] = *(const s16x8*)(ubf + ((long)comp * 64 + mt * 16 + la) * 64 + l0);
#pragma unroll
      for (int rs = 0; rs < 2; ++rs)
#pragma unroll
        for (int mt = 0; mt < 4; ++mt)
          acc[rs][mt] = __builtin_amdgcn_mfma_f32_16x16x32_bf16(za[rs], ub[mt],
                                                                acc[rs][mt], 0, 0, 0);
    }
    // q = sum_m (V[r][m] - t_m)^2 ; reduce across the 16-lane column group
#pragma unroll
    for (int rs = 0; rs < 2; ++rs)
#pragma unroll
      for (int rg = 0; rg < 4; ++rg) {
        float qv = 0.f;
#pragma unroll
        for (int mt = 0; mt < 4; ++mt) {
          float d0 = acc[rs][mt][rg] - tvv[mt];
          qv = fmaf(d0, d0, qv);
        }
        qv += __shfl_xor(qv, 1);
        qv += __shfl_xor(qv, 2);
        qv += __shfl_xor(qv, 4);
        qv += __shfl_xor(qv, 8);
        float lg = cst - 0.5f * qv;
        float Mn = fmaxf(M[rs][rg], lg);
        S[rs][rg] = S[rs][rg] * __expf(M[rs][rg] - Mn) + __expf(lg - Mn);
        M[rs][rg] = Mn;
      }
  }
  if (la == 0) {
#pragma unroll
    for (int rs = 0; rs < 2; ++rs)
#pragma unroll
      for (int rg = 0; rg < 4; ++rg)
        out[r0 + rs * 16 + hi * 4 + rg] = -(M[rs][rg] + __logf(S[rs][rg]));
  }
}

// ---------------------------------------------------------------------------
extern "C" void kernel_launch(void* const* d_in, const int* in_sizes, int n_in,
                              void* d_out, int out_size, void* d_ws, size_t ws_size,
                              hipStream_t stream) {
  const float* z = (const float*)d_in[0];
  const float* gamma = (const float*)d_in[1];
  float* out = (float*)d_out;
  char* ws = (char*)d_ws;
  unsigned short* zbf = (unsigned short*)(ws + OFF_ZBF);
  unsigned short* ztbf = (unsigned short*)(ws + OFF_ZT);
  unsigned short* sgbf = (unsigned short*)(ws + OFF_SG);
  float* s2p = (float*)(ws + OFF_S2P);
  float* sigf = (float*)(ws + OFF_SIG);
  unsigned short* ubf = (unsigned short*)(ws + OFF_UBF);
  float* f32a = (float*)(ws + OFF_F32);
  float* gsum = f32a;
  float* s1 = f32a + 16;
  float* tvec = f32a + 16 + 1024;
  float* ck = f32a + 16 + 2048;

  hipMemsetAsync(gsum, 0, (16 + 1024) * sizeof(float), stream);
  hipLaunchKernelGGL(prep_kernel, dim3(256), dim3(256), 0, stream,
                     z, gamma, zbf, ztbf, sgbf, gsum, s1);
  hipLaunchKernelGGL(stats_kernel, dim3(512), dim3(256), 0, stream,
                     ztbf, sgbf, s2p);
  hipLaunchKernelGGL(reduce_kernel, dim3(256), dim3(256), 0, stream,
                     s2p, gsum, s1, sigf);
  hipLaunchKernelGGL(cholinv_kernel, dim3(16), dim3(64), 0, stream,
                     sigf, gsum, s1, ubf, tvec, ck);
  hipLaunchKernelGGL(energy_kernel, dim3(512), dim3(256), 0, stream,
                     zbf, ubf, tvec, ck, out);
}